// Round 3
// baseline (455.224 us; speedup 1.0000x reference)
//
#include <hip/hip_runtime.h>
#include <hip/hip_cooperative_groups.h>

namespace cg = cooperative_groups;

// Output tile 64x64 per unit, input tile 36x36 (32 + 4 halo, 4-tap bicubic).
constexpr int IT  = 36;
constexpr int ITP = 37;   // sIn row stride (+1 pad)
constexpr int STP = 68;   // sT row stride: 16B-aligned, non-pow2 bank stride

// Bicubic (a = -0.75) x2-upsample phase weights, src = 0.5*i - 0.25.
#define W0 (-0.03515625f)
#define W1 ( 0.26171875f)
#define W2 ( 0.87890625f)
#define W3 (-0.10546875f)

// ---------------------------------------------------------------------------
// Shared tile pipeline: load clamped 36x36 input tile -> horizontal upsample
// to 36x64 -> vertical upsample; caller consumes the 4x float4 per thread.
// Thread map: g = t&15 owns cols 4g..4g+3; rs = t>>4 owns rows rs+16k.
// ---------------------------------------------------------------------------
template <typename F>
__device__ __forceinline__ void tile_pipeline(
    const float* __restrict__ src, int tx, int ty, int t,
    float (&sIn)[IT][ITP], float (&sT)[IT][STP],
    float a0, float a1, float a2, float a3, int b0, int g, F&& consume)
{
    const int rin0 = ty * 32 - 2;
    const int cin0 = tx * 32 - 2;

    for (int idx = t; idx < IT * IT; idx += 256) {
        int r  = idx / IT;
        int cc = idx - r * IT;
        int gr = min(max(rin0 + r, 0), 255);
        int gc = min(max(cin0 + cc, 0), 255);
        sIn[r][cc] = src[gr * 256 + gc];
    }
    __syncthreads();

    for (int r = t >> 4; r < IT; r += 16) {
        float x0 = sIn[r][2 * g + 0];
        float x1 = sIn[r][2 * g + 1];
        float x2 = sIn[r][2 * g + 2];
        float x3 = sIn[r][2 * g + 3];
        float x4 = sIn[r][2 * g + 4];
        float x5 = sIn[r][2 * g + 5];
        float4 v;
        v.x = W0 * x0 + W1 * x1 + W2 * x2 + W3 * x3;
        v.y = W3 * x1 + W2 * x2 + W1 * x3 + W0 * x4;
        v.z = W0 * x1 + W1 * x2 + W2 * x3 + W3 * x4;
        v.w = W3 * x2 + W2 * x3 + W1 * x4 + W0 * x5;
        *(float4*)&sT[r][4 * g] = v;
    }
    __syncthreads();

#pragma unroll
    for (int it = 0; it < 4; ++it) {
        const int base = b0 + 8 * it;
        float4 q0 = *(const float4*)&sT[base + 0][4 * g];
        float4 q1 = *(const float4*)&sT[base + 1][4 * g];
        float4 q2 = *(const float4*)&sT[base + 2][4 * g];
        float4 q3 = *(const float4*)&sT[base + 3][4 * g];
        float4 v;
        v.x = a0 * q0.x + a1 * q1.x + a2 * q2.x + a3 * q3.x;
        v.y = a0 * q0.y + a1 * q1.y + a2 * q2.y + a3 * q3.y;
        v.z = a0 * q0.z + a1 * q1.z + a2 * q2.z + a3 * q3.z;
        v.w = a0 * q0.w + a1 * q1.w + a2 * q2.w + a3 * q3.w;
        consume(it, v);
    }
}

__device__ __forceinline__ void block_minmax(int t, float& mn, float& mx) {
    for (int off = 32; off > 0; off >>= 1) {
        mn = fminf(mn, __shfl_down(mn, off, 64));
        mx = fmaxf(mx, __shfl_down(mx, off, 64));
    }
    __shared__ float wmn[4], wmx[4];
    const int wv = t >> 6;
    if ((t & 63) == 0) { wmn[wv] = mn; wmx[wv] = mx; }
    __syncthreads();
    mn = fminf(fminf(wmn[0], wmn[1]), fminf(wmn[2], wmn[3]));
    mx = fmaxf(fmaxf(wmx[0], wmx[1]), fmaxf(wmx[2], wmx[3]));
}

// ---------------------------------------------------------------------------
// Cooperative single-pass kernel: 1024 blocks x 4 units. Values stay in
// registers across grid.sync(); compute happens exactly once.
// ---------------------------------------------------------------------------
__global__ __launch_bounds__(256, 4)
void qwt_coop(const float* __restrict__ LL, float* __restrict__ out,
              float* __restrict__ pmin, float* __restrict__ pmax)
{
    __shared__ float sIn[IT][ITP];
    __shared__ float sT[IT][STP];

    const int t   = threadIdx.x;
    const int blk = blockIdx.x;       // 0..1023

    const int g  = t & 15;
    const int rs = t >> 4;
    const int od = rs & 1;
    const int b0 = (rs >> 1) + od;
    const float a0 = od ? W3 : W0;
    const float a1 = od ? W2 : W1;
    const float a2 = od ? W1 : W2;
    const float a3 = od ? W0 : W3;

    float4 vv[4][4];                  // [unit][row-group] value stash
    float mn = 1e30f, mx = -1e30f;

#pragma unroll
    for (int u = 0; u < 4; ++u) {
        const int unit = blk * 4 + u; // 0..4095
        const int tx = unit & 7;
        const int ty = (unit >> 3) & 7;
        const int pl = unit >> 6;
        const float* src = LL + (size_t)((pl >> 3) * 32 + (pl & 7)) * (256 * 256);
        __syncthreads();              // protect sIn/sT reuse across units
        tile_pipeline(src, tx, ty, t, sIn, sT, a0, a1, a2, a3, b0, g,
            [&](int it, float4 v) {
                vv[u][it] = v;
                mn = fminf(mn, fminf(fminf(v.x, v.y), fminf(v.z, v.w)));
                mx = fmaxf(mx, fmaxf(fmaxf(v.x, v.y), fmaxf(v.z, v.w)));
            });
    }

    block_minmax(t, mn, mx);
    if (t == 0) { pmin[blk] = mn; pmax[blk] = mx; }
    __threadfence();                  // device-scope release of partials

    cg::this_grid().sync();

    // Every block reduces the 1024 partials (L2/L3-hot broadcast read).
    float m = 1e30f, M = -1e30f;
#pragma unroll
    for (int k = 0; k < 4; ++k) {
        m = fminf(m, pmin[t + 256 * k]);
        M = fmaxf(M, pmax[t + 256 * k]);
    }
    __syncthreads();                  // block_minmax reuses wmn/wmx LDS
    block_minmax(t, m, M);
    const float scl = 1.0f / (M - m);

#pragma unroll
    for (int u = 0; u < 4; ++u) {
        const int unit = blk * 4 + u;
        const int tx = unit & 7;
        const int ty = (unit >> 3) & 7;
        const int pl = unit >> 6;
        float* dst = out + (size_t)pl * (512 * 512)
                   + (size_t)(ty * 64 + rs) * 512 + tx * 64 + 4 * g;
#pragma unroll
        for (int it = 0; it < 4; ++it) {
            float4 v = vv[u][it];
            float4 o;
            o.x = (v.x - m) * scl;
            o.y = (v.y - m) * scl;
            o.z = (v.z - m) * scl;
            o.w = (v.w - m) * scl;
            *(float4*)(dst + (size_t)(16 * it) * 512) = o;
        }
    }
}

// ---------------------------------------------------------------------------
// Fallback path (proven in round 2): min/max pass, tiny reduce, store pass.
// ---------------------------------------------------------------------------
template <int MODE>
__global__ __launch_bounds__(256)
void qwt_up2(const float* __restrict__ LL, float* __restrict__ out,
             float* __restrict__ pmin, float* __restrict__ pmax,
             const float* __restrict__ res)
{
    __shared__ float sIn[IT][ITP];
    __shared__ float sT[IT][STP];

    const int t  = threadIdx.x;
    const int tx = blockIdx.x;
    const int ty = blockIdx.y;
    const int pl = blockIdx.z;
    const float* src = LL + (size_t)((pl >> 3) * 32 + (pl & 7)) * (256 * 256);

    const int g  = t & 15;
    const int rs = t >> 4;
    const int od = rs & 1;
    const int b0 = (rs >> 1) + od;
    const float a0 = od ? W3 : W0;
    const float a1 = od ? W2 : W1;
    const float a2 = od ? W1 : W2;
    const float a3 = od ? W0 : W3;

    float mn = 1e30f, mx = -1e30f;
    float sub = 0.f, scl = 1.f;
    if (MODE == 1) { sub = res[0]; scl = res[1]; }
    float* dst = out + (size_t)pl * (512 * 512)
               + (size_t)(ty * 64 + rs) * 512 + tx * 64 + 4 * g;

    tile_pipeline(src, tx, ty, t, sIn, sT, a0, a1, a2, a3, b0, g,
        [&](int it, float4 v) {
            if (MODE == 0) {
                mn = fminf(mn, fminf(fminf(v.x, v.y), fminf(v.z, v.w)));
                mx = fmaxf(mx, fmaxf(fmaxf(v.x, v.y), fmaxf(v.z, v.w)));
            } else {
                float4 o;
                o.x = (v.x - sub) * scl;
                o.y = (v.y - sub) * scl;
                o.z = (v.z - sub) * scl;
                o.w = (v.w - sub) * scl;
                *(float4*)(dst + (size_t)(16 * it) * 512) = o;
            }
        });

    if (MODE == 0) {
        block_minmax(t, mn, mx);
        if (t == 0) {
            const int p = (pl * 8 + ty) * 8 + tx;
            pmin[p] = mn;
            pmax[p] = mx;
        }
    }
}

__global__ __launch_bounds__(256)
void qwt_reduce(const float* __restrict__ pmin, const float* __restrict__ pmax,
                float* __restrict__ res)
{
    const int t = threadIdx.x;
    float mn = 1e30f, mx = -1e30f;
    for (int i = t; i < 4096; i += 256) {
        mn = fminf(mn, pmin[i]);
        mx = fmaxf(mx, pmax[i]);
    }
    block_minmax(t, mn, mx);
    if (t == 0) {
        res[0] = mn;
        res[1] = 1.0f / (mx - mn);
    }
}

extern "C" void kernel_launch(void* const* d_in, const int* in_sizes, int n_in,
                              void* d_out, int out_size, void* d_ws, size_t ws_size,
                              hipStream_t stream)
{
    (void)in_sizes; (void)n_in; (void)out_size; (void)ws_size;
    const float* LL = (const float*)d_in[0];
    float* out      = (float*)d_out;

    // ws: [0,4096) mins, [4096,8192) maxs, [8192,8194) (min, 1/(max-min)).
    // Everything is written before read — 0xAA poison is harmless.
    float* pmin = (float*)d_ws;
    float* pmax = pmin + 4096;
    float* res  = pmin + 8192;

    void* args[] = { (void*)&LL, (void*)&out, (void*)&pmin, (void*)&pmax };
    hipError_t rc = hipLaunchCooperativeKernel(
        reinterpret_cast<void*>(qwt_coop), dim3(1024), dim3(256), args, 0, stream);

    if (rc != hipSuccess) {
        // Deterministic fallback: same environment -> same path every call.
        dim3 grid(8, 8, 64);
        dim3 block(256);
        qwt_up2<0><<<grid, block, 0, stream>>>(LL, nullptr, pmin, pmax, nullptr);
        qwt_reduce<<<dim3(1), block, 0, stream>>>(pmin, pmax, res);
        qwt_up2<1><<<grid, block, 0, stream>>>(LL, out, nullptr, nullptr, res);
    }
}

// Round 5
// 294.797 us; speedup vs baseline: 1.5442x; 1.5442x over previous
//
#include <hip/hip_runtime.h>

// Output tile 64x64 per block, input tile 36x36 (32 + 4 halo, 4-tap bicubic).
constexpr int IT  = 36;
constexpr int ITP = 37;   // sIn row stride (+1 pad)
constexpr int STP = 68;   // sT row stride: 16B-aligned, non-pow2 bank stride

// Bicubic (a = -0.75) x2-upsample phase weights, src = 0.5*i - 0.25.
#define W0 (-0.03515625f)
#define W1 ( 0.26171875f)
#define W2 ( 0.87890625f)
#define W3 (-0.10546875f)

// Native vector type: __builtin_nontemporal_store requires a real vector,
// not HIP_vector_type<float,4> (a struct).
typedef float vfloat4 __attribute__((ext_vector_type(4)));

// ---------------------------------------------------------------------------
// Tile pipeline: clamped 36x36 load -> horizontal upsample (36x64) ->
// vertical upsample; consume(it, v) gets 4x float4 per thread.
// Thread map: g = t&15 owns cols 4g..4g+3; rs = t>>4 owns rows rs+16k.
// ---------------------------------------------------------------------------
template <typename F>
__device__ __forceinline__ void tile_pipeline(
    const float* __restrict__ src, int tx, int ty, int t,
    float (&sIn)[IT][ITP], float (&sT)[IT][STP],
    float a0, float a1, float a2, float a3, int b0, int g, F&& consume)
{
    const int rin0 = ty * 32 - 2;
    const int cin0 = tx * 32 - 2;

    for (int idx = t; idx < IT * IT; idx += 256) {
        int r  = idx / IT;
        int cc = idx - r * IT;
        int gr = min(max(rin0 + r, 0), 255);
        int gc = min(max(cin0 + cc, 0), 255);
        sIn[r][cc] = src[gr * 256 + gc];
    }
    __syncthreads();

    for (int r = t >> 4; r < IT; r += 16) {
        float x0 = sIn[r][2 * g + 0];
        float x1 = sIn[r][2 * g + 1];
        float x2 = sIn[r][2 * g + 2];
        float x3 = sIn[r][2 * g + 3];
        float x4 = sIn[r][2 * g + 4];
        float x5 = sIn[r][2 * g + 5];
        vfloat4 v;
        v.x = W0 * x0 + W1 * x1 + W2 * x2 + W3 * x3;
        v.y = W3 * x1 + W2 * x2 + W1 * x3 + W0 * x4;
        v.z = W0 * x1 + W1 * x2 + W2 * x3 + W3 * x4;
        v.w = W3 * x2 + W2 * x3 + W1 * x4 + W0 * x5;
        *(vfloat4*)&sT[r][4 * g] = v;
    }
    __syncthreads();

#pragma unroll
    for (int it = 0; it < 4; ++it) {
        const int base = b0 + 8 * it;
        vfloat4 q0 = *(const vfloat4*)&sT[base + 0][4 * g];
        vfloat4 q1 = *(const vfloat4*)&sT[base + 1][4 * g];
        vfloat4 q2 = *(const vfloat4*)&sT[base + 2][4 * g];
        vfloat4 q3 = *(const vfloat4*)&sT[base + 3][4 * g];
        vfloat4 v = a0 * q0 + a1 * q1 + a2 * q2 + a3 * q3;
        consume(it, v);
    }
}

// Block-wide min/max; on return ALL threads hold the block result.
__device__ __forceinline__ void block_minmax(int t, float& mn, float& mx) {
    for (int off = 32; off > 0; off >>= 1) {
        mn = fminf(mn, __shfl_down(mn, off, 64));
        mx = fmaxf(mx, __shfl_down(mx, off, 64));
    }
    __shared__ float wmn[4], wmx[4];
    const int wv = t >> 6;
    if ((t & 63) == 0) { wmn[wv] = mn; wmx[wv] = mx; }
    __syncthreads();
    mn = fminf(fminf(wmn[0], wmn[1]), fminf(wmn[2], wmn[3]));
    mx = fmaxf(fmaxf(wmx[0], wmx[1]), fmaxf(wmx[2], wmx[3]));
}

// Pass 1: per-block min/max partials over the upsampled tile.
__global__ __launch_bounds__(256)
void qwt_pass1(const float* __restrict__ LL,
               float* __restrict__ pmin, float* __restrict__ pmax)
{
    __shared__ float sIn[IT][ITP];
    __shared__ float sT[IT][STP];

    const int t  = threadIdx.x;
    const int tx = blockIdx.x;
    const int ty = blockIdx.y;
    const int pl = blockIdx.z;
    const float* src = LL + (size_t)((pl >> 3) * 32 + (pl & 7)) * (256 * 256);

    const int g  = t & 15;
    const int rs = t >> 4;
    const int od = rs & 1;
    const int b0 = (rs >> 1) + od;
    const float a0 = od ? W3 : W0;
    const float a1 = od ? W2 : W1;
    const float a2 = od ? W1 : W2;
    const float a3 = od ? W0 : W3;

    float mn = 1e30f, mx = -1e30f;
    tile_pipeline(src, tx, ty, t, sIn, sT, a0, a1, a2, a3, b0, g,
        [&](int, vfloat4 v) {
            mn = fminf(mn, fminf(fminf(v.x, v.y), fminf(v.z, v.w)));
            mx = fmaxf(mx, fmaxf(fmaxf(v.x, v.y), fmaxf(v.z, v.w)));
        });

    block_minmax(t, mn, mx);
    if (t == 0) {
        const int p = (pl * 8 + ty) * 8 + tx;
        pmin[p] = mn;
        pmax[p] = mx;
    }
}

// Pass 2: every block reduces the 4096 partials (L2-hot broadcast), then
// recomputes its tile, normalizes, and streams the result out (nontemporal).
__global__ __launch_bounds__(256)
void qwt_pass2(const float* __restrict__ LL, float* __restrict__ out,
               const float* __restrict__ pmin, const float* __restrict__ pmax)
{
    __shared__ float sIn[IT][ITP];
    __shared__ float sT[IT][STP];

    const int t  = threadIdx.x;
    const int tx = blockIdx.x;
    const int ty = blockIdx.y;
    const int pl = blockIdx.z;
    const float* src = LL + (size_t)((pl >> 3) * 32 + (pl & 7)) * (256 * 256);

    // Reduce the 4096-entry partial arrays within this block.
    float m = 1e30f, M = -1e30f;
#pragma unroll
    for (int k = 0; k < 16; ++k) {
        m = fminf(m, pmin[t + 256 * k]);
        M = fmaxf(M, pmax[t + 256 * k]);
    }
    block_minmax(t, m, M);
    const float sub = m;
    const float scl = 1.0f / (M - m);

    const int g  = t & 15;
    const int rs = t >> 4;
    const int od = rs & 1;
    const int b0 = (rs >> 1) + od;
    const float a0 = od ? W3 : W0;
    const float a1 = od ? W2 : W1;
    const float a2 = od ? W1 : W2;
    const float a3 = od ? W0 : W3;

    float* dst = out + (size_t)pl * (512 * 512)
               + (size_t)(ty * 64 + rs) * 512 + tx * 64 + 4 * g;

    tile_pipeline(src, tx, ty, t, sIn, sT, a0, a1, a2, a3, b0, g,
        [&](int it, vfloat4 v) {
            vfloat4 o = (v - sub) * scl;
            // Output is write-once, never re-read: bypass cache pollution.
            __builtin_nontemporal_store(o, (vfloat4*)(dst + (size_t)(16 * it) * 512));
        });
}

extern "C" void kernel_launch(void* const* d_in, const int* in_sizes, int n_in,
                              void* d_out, int out_size, void* d_ws, size_t ws_size,
                              hipStream_t stream)
{
    (void)in_sizes; (void)n_in; (void)out_size; (void)ws_size;
    const float* LL = (const float*)d_in[0];
    float* out      = (float*)d_out;

    // ws: [0,4096) per-block mins, [4096,8192) per-block maxs.
    // All slots written by pass1 before pass2 reads them — 0xAA poison is fine.
    float* pmin = (float*)d_ws;
    float* pmax = pmin + 4096;

    dim3 grid(8, 8, 64);
    dim3 block(256);
    qwt_pass1<<<grid, block, 0, stream>>>(LL, pmin, pmax);
    qwt_pass2<<<grid, block, 0, stream>>>(LL, out, pmin, pmax);
}